// Round 10
// baseline (406.467 us; speedup 1.0000x reference)
//
#include <hip/hip_runtime.h>
#include <hip/hip_bf16.h>

// Problem constants (from reference)
#define Nn   40000
#define Ee   640000
#define Gg   64
#define INF  128
#define Hh   256
#define OUTF 128

#define NBLK_N 157   // ceil(40000/256)

typedef _Float16 half8 __attribute__((ext_vector_type(8)));
typedef float    f32x4 __attribute__((ext_vector_type(4)));

// ---------------- degree histogram ----------------
__global__ __launch_bounds__(256) void k_count(const int* __restrict__ dst, int* __restrict__ cnt) {
    int e = blockIdx.x * 256 + threadIdx.x;
    if (e < Ee) atomicAdd(&cnt[dst[e]], 1);
}

// ---------------- scan1 + dis + cnt re-zero (fused) ----------------
__global__ __launch_bounds__(256)
void k_scan1(int* __restrict__ cnt, int* __restrict__ offs, int* __restrict__ partial,
             float* __restrict__ dis) {
    __shared__ int sm[256];
    int i = blockIdx.x * 256 + threadIdx.x;
    int v = 0;
    if (i < Nn) {
        v = cnt[i];
        dis[i] = rsqrtf((float)v + 1.0f);
        cnt[i] = 0;                       // re-zero for use as k_fill cursor
    }
    sm[threadIdx.x] = v;
    __syncthreads();
#pragma unroll
    for (int d = 1; d < 256; d <<= 1) {
        int t = (threadIdx.x >= d) ? sm[threadIdx.x - d] : 0;
        __syncthreads();
        sm[threadIdx.x] += t;
        __syncthreads();
    }
    if (i < Nn) offs[i] = sm[threadIdx.x] - v;
    if (threadIdx.x == 255) partial[blockIdx.x] = sm[255];
}

__global__ __launch_bounds__(256)
void k_scan2(int* __restrict__ partial) {
    __shared__ int sm[256];
    int v = (threadIdx.x < NBLK_N) ? partial[threadIdx.x] : 0;
    sm[threadIdx.x] = v;
    __syncthreads();
#pragma unroll
    for (int d = 1; d < 256; d <<= 1) {
        int t = (threadIdx.x >= d) ? sm[threadIdx.x - d] : 0;
        __syncthreads();
        sm[threadIdx.x] += t;
        __syncthreads();
    }
    if (threadIdx.x < NBLK_N) partial[threadIdx.x] = sm[threadIdx.x] - v;
}

__global__ __launch_bounds__(256)
void k_scan3(int* __restrict__ offs, const int* __restrict__ partial) {
    int i = blockIdx.x * 256 + threadIdx.x;
    if (i < Nn) offs[i] += partial[blockIdx.x];
    if (i == 0) offs[Nn] = Ee;
}

// ---------------- CSR fill: bucket src ids by dst ----------------
__global__ __launch_bounds__(256)
void k_fill(const int* __restrict__ src, const int* __restrict__ dst,
            const int* __restrict__ offs, int* __restrict__ cursor,
            unsigned short* __restrict__ src_sorted) {
    int e = blockIdx.x * 256 + threadIdx.x;
    if (e >= Ee) return;
    int d = dst[e];
    int pos = offs[d] + atomicAdd(&cursor[d], 1);
    src_sorted[pos] = (unsigned short)src[e];
}

// ---------------- fused conversions: x->fp16, 3x W->Wt fp16, ge_accum zero ----------------
// block ranges: [0,5000) x | [5000,5128) W_in | [5128,5384) W_mid | [5384,5512) W_out | [5512,5544) zero
__global__ __launch_bounds__(256)
void k_cvt_all(const float* __restrict__ x, _Float16* __restrict__ xh,
               const float* __restrict__ W_in,  _Float16* __restrict__ Wt_in,
               const float* __restrict__ W_mid, _Float16* __restrict__ Wt_mid,
               const float* __restrict__ W_out, _Float16* __restrict__ Wt_out,
               float* __restrict__ ge_accum) {
    int bid = blockIdx.x;
    int tid = threadIdx.x;
    if (bid < 5000) {
        int i = (bid * 256 + tid) * 4;           // 5,120,000 elems exactly
        float4 v = *(const float4*)&x[i];
        xh[i + 0] = (_Float16)v.x;
        xh[i + 1] = (_Float16)v.y;
        xh[i + 2] = (_Float16)v.z;
        xh[i + 3] = (_Float16)v.w;
    } else if (bid < 5128) {                     // W_in [128][256] -> Wt [256][128]
        int idx = (bid - 5000) * 256 + tid;      // < 32768
        int n = idx >> 7, k = idx & 127;
        Wt_in[idx] = (_Float16)W_in[(size_t)k * Hh + n];
    } else if (bid < 5384) {                     // W_mid [256][256] -> Wt [256][256]
        int idx = (bid - 5128) * 256 + tid;      // < 65536
        int n = idx >> 8, k = idx & 255;
        Wt_mid[idx] = (_Float16)W_mid[(size_t)k * Hh + n];
    } else if (bid < 5512) {                     // W_out [256][128] -> Wt [128][256]
        int idx = (bid - 5384) * 256 + tid;      // < 32768
        int n = idx >> 8, k = idx & 255;
        Wt_out[idx] = (_Float16)W_out[(size_t)k * OUTF + n];
    } else {                                     // ge_accum zero (8192)
        int idx = (bid - 5512) * 256 + tid;
        ge_accum[idx] = 0.0f;
    }
}

// ---------------- fp16 MFMA GEMM: C16[M,N] = (half)(dis[row] * (A @ Wt^T)) ----------------
__global__ __launch_bounds__(256)
void k_gemm_mfma(const _Float16* __restrict__ A, const _Float16* __restrict__ Wt,
                 const float* __restrict__ dis, _Float16* __restrict__ C16,
                 int M, int N, int K) {
    __shared__ _Float16 Alds[128 * 40];
    __shared__ _Float16 Blds[128 * 40];
    const int tid = threadIdx.x;
    const int lane = tid & 63;
    const int waveId = tid >> 6;
    const int waveRow = waveId >> 1;
    const int waveCol = waveId & 1;
    const int quad = lane >> 4;
    const int m16 = lane & 15;
    const int rowBase = blockIdx.x * 128;
    const int colBase = blockIdx.y * 128;

    const int sRow  = tid >> 1;
    const int sKoff = (tid & 1) * 16;

    int gr = rowBase + sRow; if (gr >= M) gr = M - 1;
    const int gn = colBase + sRow;

    f32x4 acc[4][4];
#pragma unroll
    for (int i = 0; i < 4; ++i)
#pragma unroll
        for (int j = 0; j < 4; ++j)
            acc[i][j] = (f32x4){0.0f, 0.0f, 0.0f, 0.0f};

    for (int k0 = 0; k0 < K; k0 += 32) {
        const uint4* ap = (const uint4*)(A  + (size_t)gr * K + k0 + sKoff);
        const uint4* bp = (const uint4*)(Wt + (size_t)gn * K + k0 + sKoff);
        uint4 a0 = ap[0], a1 = ap[1];
        uint4 b0 = bp[0], b1 = bp[1];
        __syncthreads();
        *(uint4*)&Alds[sRow * 40 + sKoff]     = a0;
        *(uint4*)&Alds[sRow * 40 + sKoff + 8] = a1;
        *(uint4*)&Blds[sRow * 40 + sKoff]     = b0;
        *(uint4*)&Blds[sRow * 40 + sKoff + 8] = b1;
        __syncthreads();

        half8 a_frag[4], b_frag[4];
#pragma unroll
        for (int rt = 0; rt < 4; ++rt)
            a_frag[rt] = *(const half8*)&Alds[(waveRow * 64 + rt * 16 + m16) * 40 + quad * 8];
#pragma unroll
        for (int ct = 0; ct < 4; ++ct)
            b_frag[ct] = *(const half8*)&Blds[(waveCol * 64 + ct * 16 + m16) * 40 + quad * 8];
#pragma unroll
        for (int rt = 0; rt < 4; ++rt)
#pragma unroll
            for (int ct = 0; ct < 4; ++ct)
                acc[rt][ct] = __builtin_amdgcn_mfma_f32_16x16x32_f16(
                    a_frag[rt], b_frag[ct], acc[rt][ct], 0, 0, 0);
    }

#pragma unroll
    for (int rt = 0; rt < 4; ++rt) {
        const int rb = rowBase + waveRow * 64 + rt * 16 + quad * 4;
#pragma unroll
        for (int r = 0; r < 4; ++r) {
            const int row = rb + r;
            if (row < M) {
                const float s = dis[row];
#pragma unroll
                for (int ct = 0; ct < 4; ++ct) {
                    const int col = colBase + waveCol * 64 + ct * 16 + m16;
                    C16[(size_t)row * N + col] = (_Float16)(s * acc[rt][ct][r]);
                }
            }
        }
    }
}

// ---------------- CSR gather on fp16 pre-scaled rows, non-temporal row loads ----------------
// out[n] = dis[n]*(sum h'[src] + h'[n]) + bias (+ReLU), fp32 accumulate.
// Gather invariant measured R3-R8: ~11.5 CU-cycles per 128B line touched, layout-
// and residency-independent => suspect L1 allocate/fill path. nt (no-allocate)
// loads test that hypothesis; FETCH_SIZE tells us if L2 policy degraded instead.
template <int HH, bool RELU, bool H16OUT>
__global__ __launch_bounds__(256)
void k_gatherh(const int* __restrict__ offs, const unsigned short* __restrict__ srcs,
               const float* __restrict__ dis, const _Float16* __restrict__ hp,
               const float* __restrict__ bias, void* __restrict__ outv) {
    constexpr int V = HH / 64;   // 4 (H=256) or 2 (H=128)
    typedef _Float16 halfv __attribute__((ext_vector_type(V)));
    int n = blockIdx.x * 4 + (threadIdx.x >> 6);
    if (n >= Nn) return;
    int lane = threadIdx.x & 63;
    int col = lane * V;
    int b = __builtin_amdgcn_readfirstlane(offs[n]);
    int e = __builtin_amdgcn_readfirstlane(offs[n + 1]);

    auto ldrow = [&](int s) -> halfv {
        const _Float16* p = hp + (size_t)s * HH + col;
        if constexpr (V == 4) {
            unsigned long long u = __builtin_nontemporal_load((const unsigned long long*)p);
            return __builtin_bit_cast(halfv, u);
        } else {
            unsigned int u = __builtin_nontemporal_load((const unsigned int*)p);
            return __builtin_bit_cast(halfv, u);
        }
    };

    float acc[V];
    {
        halfv sv = *(const halfv*)(hp + (size_t)n * HH + col);   // self row h'[n]
#pragma unroll
        for (int j = 0; j < V; ++j) acc[j] = (float)sv[j];
    }

    int i = b;
    for (; i + 4 <= e; i += 4) {
        int s0 = srcs[i], s1 = srcs[i + 1], s2 = srcs[i + 2], s3 = srcs[i + 3];
        halfv v0 = ldrow(s0);
        halfv v1 = ldrow(s1);
        halfv v2 = ldrow(s2);
        halfv v3 = ldrow(s3);
#pragma unroll
        for (int j = 0; j < V; ++j)
            acc[j] += (float)v0[j] + (float)v1[j] + (float)v2[j] + (float)v3[j];
    }
    for (; i < e; ++i) {
        halfv v0 = ldrow(srcs[i]);
#pragma unroll
        for (int j = 0; j < V; ++j) acc[j] += (float)v0[j];
    }

    float dn = dis[n];
    float r[V];
#pragma unroll
    for (int j = 0; j < V; ++j) {
        r[j] = dn * acc[j] + bias[col + j];
        if (RELU) r[j] = fmaxf(r[j], 0.0f);
    }
    if constexpr (H16OUT) {
        halfv hv;
#pragma unroll
        for (int j = 0; j < V; ++j) hv[j] = (_Float16)r[j];
        *(halfv*)((_Float16*)outv + (size_t)n * HH + col) = hv;
    } else {
        if constexpr (V == 4) {
            *(float4*)((float*)outv + (size_t)n * HH + col) = make_float4(r[0], r[1], r[2], r[3]);
        } else {
            *(float2*)((float*)outv + (size_t)n * HH + col) = make_float2(r[0], r[1]);
        }
    }
}

// ---------------- pool phase 1: chunked segment-aware accumulation ----------------
__global__ __launch_bounds__(256)
void k_pool_accum(const float* __restrict__ emb, const int* __restrict__ batch,
                  float* __restrict__ ge_accum) {
    int n0 = blockIdx.x * 64;
    int nend = min(n0 + 64, Nn);
    int sub = threadIdx.x >> 6;
    int col = (threadIdx.x & 63) * 2;
    float ax = 0.0f, ay = 0.0f;
    int cur_g = -1;
    for (int n = n0 + sub; n < nend; n += 4) {
        int g = batch[n];
        if (g != cur_g) {
            if (cur_g >= 0) {
                unsafeAtomicAdd(&ge_accum[cur_g * OUTF + col], ax);
                unsafeAtomicAdd(&ge_accum[cur_g * OUTF + col + 1], ay);
            }
            cur_g = g; ax = 0.0f; ay = 0.0f;
        }
        float2 v = *(const float2*)&emb[(size_t)n * OUTF + col];
        ax += v.x; ay += v.y;
    }
    if (cur_g >= 0) {
        unsafeAtomicAdd(&ge_accum[cur_g * OUTF + col], ax);
        unsafeAtomicAdd(&ge_accum[cur_g * OUTF + col + 1], ay);
    }
}

// ---------------- fused pool finalize + logits (single block) ----------------
__global__ __launch_bounds__(256)
void k_pool_fin(const float* __restrict__ ge_accum, const int* __restrict__ batch,
                const float* __restrict__ Wc, const float* __restrict__ bc,
                float* __restrict__ ge_out, float* __restrict__ lg_out) {
    __shared__ float ge_s[Gg * OUTF];
    __shared__ int seg[Gg + 1];
    int t = threadIdx.x;
    if (t <= Gg) {                       // first index with batch >= t
        int lo = 0, hi = Nn;
        while (lo < hi) { int mid = (lo + hi) >> 1; if (batch[mid] < t) lo = mid + 1; else hi = mid; }
        seg[t] = lo;
    }
    __syncthreads();
    for (int idx = t; idx < Gg * OUTF; idx += 256) {
        int g = idx >> 7;
        float cnt = (float)(seg[g + 1] - seg[g]);
        float v = ge_accum[idx] / fmaxf(cnt, 1.0f);
        ge_s[idx] = v;
        ge_out[idx] = v;
    }
    __syncthreads();
    if (t < 128) {
        int g = t >> 1, c = t & 1;
        float s = bc[c];
        for (int k = 0; k < 128; ++k) s += ge_s[g * 128 + k] * Wc[k * 2 + c];
        lg_out[t] = s;
    }
}

extern "C" void kernel_launch(void* const* d_in, const int* in_sizes, int n_in,
                              void* d_out, int out_size, void* d_ws, size_t ws_size,
                              hipStream_t stream) {
    const float* x     = (const float*)d_in[0];
    const int*   ei    = (const int*)d_in[1];
    const int*   batch = (const int*)d_in[2];
    const float* W_in  = (const float*)d_in[3];
    const float* b_in  = (const float*)d_in[4];
    const float* W_mid = (const float*)d_in[5];
    const float* b_mid = (const float*)d_in[6];
    const float* W_out = (const float*)d_in[7];
    const float* b_out = (const float*)d_in[8];
    const float* W_cls = (const float*)d_in[9];
    const float* b_cls = (const float*)d_in[10];

    const int* src = ei;
    const int* dst = ei + Ee;

    // workspace layout (4B units), total ~53 MB (< proven 83.7 MB envelope)
    float* ws = (float*)d_ws;
    float* dis      = ws;                          // 40000
    int*   cnt      = (int*)(ws + 40000);          // 40000
    int*   offs     = (int*)(ws + 80000);          // 40064
    int*   partial  = (int*)(ws + 120064);         // 192
    float* ge_accum = ws + 120256;                 // 8192
    unsigned short* src_sorted = (unsigned short*)(ws + 128448);   // 640000 ushort
    _Float16* xh     = (_Float16*)(ws + 448448);   // 40000*128 h
    _Float16* Wt_in  = (_Float16*)(ws + 3008448);  // 256*128 h
    _Float16* Wt_mid = (_Float16*)(ws + 3024832);  // 256*256 h
    _Float16* Wt_out = (_Float16*)(ws + 3057600);  // 128*256 h
    _Float16* hA     = (_Float16*)(ws + 3073984);  // 40000*256 h
    _Float16* actA   = (_Float16*)(ws + 8193984);  // 40000*256 h
    // end = 13,313,984 floats = 53.3 MB

    float* out    = (float*)d_out;
    float* ge_out = out + (size_t)Nn * OUTF;
    float* lg_out = ge_out + Gg * OUTF;

    const int nBlkE = (Ee + 255) / 256;
    const int gRows = (Nn + 127) / 128;            // 313
    const int nBlkG = (Nn + 3) / 4;                // 10000

    // ---- CSR build (6 dispatches incl. 1 memset) ----
    (void)hipMemsetAsync(cnt, 0, Nn * sizeof(int), stream);
    k_count<<<nBlkE, 256, 0, stream>>>(dst, cnt);
    k_scan1<<<NBLK_N, 256, 0, stream>>>(cnt, offs, partial, dis);
    k_scan2<<<1, 256, 0, stream>>>(partial);
    k_scan3<<<NBLK_N, 256, 0, stream>>>(offs, partial);
    k_fill<<<nBlkE, 256, 0, stream>>>(src, dst, offs, cnt, src_sorted);

    // ---- all fp16 conversions + ge_accum zero (1 dispatch) ----
    k_cvt_all<<<5544, 256, 0, stream>>>(x, xh, W_in, Wt_in, W_mid, Wt_mid, W_out, Wt_out, ge_accum);

    // ---- layer 1 ----
    k_gemm_mfma<<<dim3(gRows, Hh / 128), 256, 0, stream>>>(xh, Wt_in, dis, hA, Nn, Hh, INF);
    k_gatherh<Hh, true, true><<<nBlkG, 256, 0, stream>>>(offs, src_sorted, dis, hA, b_in, actA);

    // ---- layer 2 ----
    k_gemm_mfma<<<dim3(gRows, Hh / 128), 256, 0, stream>>>(actA, Wt_mid, dis, hA, Nn, Hh, Hh);
    k_gatherh<Hh, true, true><<<nBlkG, 256, 0, stream>>>(offs, src_sorted, dis, hA, b_mid, actA);

    // ---- layer 3 -> node embeddings (fp32) in d_out ----
    k_gemm_mfma<<<dim3(gRows, OUTF / 128), 256, 0, stream>>>(actA, Wt_out, dis, hA, Nn, OUTF, Hh);
    k_gatherh<OUTF, false, false><<<nBlkG, 256, 0, stream>>>(offs, src_sorted, dis, hA, b_out, out);

    // ---- pooling + classifier (2 dispatches) ----
    k_pool_accum<<<(Nn + 63) / 64, 256, 0, stream>>>(out, batch, ge_accum);
    k_pool_fin<<<1, 256, 0, stream>>>(ge_accum, batch, W_cls, b_cls, ge_out, lg_out);
}

// Round 12
// 331.157 us; speedup vs baseline: 1.2274x; 1.2274x over previous
//
#include <hip/hip_runtime.h>
#include <hip/hip_bf16.h>

// Problem constants (from reference)
#define Nn   40000
#define Ee   640000
#define Gg   64
#define INF  128
#define Hh   256
#define OUTF 128

#define NBLK_N 157   // ceil(40000/256)

typedef _Float16 half8 __attribute__((ext_vector_type(8)));
typedef float    f32x4 __attribute__((ext_vector_type(4)));

// ---------------- degree histogram ----------------
__global__ __launch_bounds__(256) void k_count(const int* __restrict__ dst, int* __restrict__ cnt) {
    int e = blockIdx.x * 256 + threadIdx.x;
    if (e < Ee) atomicAdd(&cnt[dst[e]], 1);
}

// ---------------- scan1 + dis + cnt re-zero (fused) ----------------
__global__ __launch_bounds__(256)
void k_scan1(int* __restrict__ cnt, int* __restrict__ offs, int* __restrict__ partial,
             float* __restrict__ dis) {
    __shared__ int sm[256];
    int i = blockIdx.x * 256 + threadIdx.x;
    int v = 0;
    if (i < Nn) {
        v = cnt[i];
        dis[i] = rsqrtf((float)v + 1.0f);
        cnt[i] = 0;                       // re-zero for use as k_fill cursor
    }
    sm[threadIdx.x] = v;
    __syncthreads();
#pragma unroll
    for (int d = 1; d < 256; d <<= 1) {
        int t = (threadIdx.x >= d) ? sm[threadIdx.x - d] : 0;
        __syncthreads();
        sm[threadIdx.x] += t;
        __syncthreads();
    }
    if (i < Nn) offs[i] = sm[threadIdx.x] - v;
    if (threadIdx.x == 255) partial[blockIdx.x] = sm[255];
}

__global__ __launch_bounds__(256)
void k_scan2(int* __restrict__ partial) {
    __shared__ int sm[256];
    int v = (threadIdx.x < NBLK_N) ? partial[threadIdx.x] : 0;
    sm[threadIdx.x] = v;
    __syncthreads();
#pragma unroll
    for (int d = 1; d < 256; d <<= 1) {
        int t = (threadIdx.x >= d) ? sm[threadIdx.x - d] : 0;
        __syncthreads();
        sm[threadIdx.x] += t;
        __syncthreads();
    }
    if (threadIdx.x < NBLK_N) partial[threadIdx.x] = sm[threadIdx.x] - v;
}

__global__ __launch_bounds__(256)
void k_scan3(int* __restrict__ offs, const int* __restrict__ partial) {
    int i = blockIdx.x * 256 + threadIdx.x;
    if (i < Nn) offs[i] += partial[blockIdx.x];
    if (i == 0) offs[Nn] = Ee;
}

// ---------------- CSR fill: bucket src ids by dst ----------------
__global__ __launch_bounds__(256)
void k_fill(const int* __restrict__ src, const int* __restrict__ dst,
            const int* __restrict__ offs, int* __restrict__ cursor,
            unsigned short* __restrict__ src_sorted) {
    int e = blockIdx.x * 256 + threadIdx.x;
    if (e >= Ee) return;
    int d = dst[e];
    int pos = offs[d] + atomicAdd(&cursor[d], 1);
    src_sorted[pos] = (unsigned short)src[e];
}

// ---------------- fused conversions: xs=fp16(dis*x), 3x W->Wt fp16, ge_accum zero ----------------
// block ranges: [0,5000) x | [5000,5128) W_in | [5128,5384) W_mid | [5384,5512) W_out | [5512,5544) zero
__global__ __launch_bounds__(256)
void k_cvt_all(const float* __restrict__ x, const float* __restrict__ dis,
               _Float16* __restrict__ xs,
               const float* __restrict__ W_in,  _Float16* __restrict__ Wt_in,
               const float* __restrict__ W_mid, _Float16* __restrict__ Wt_mid,
               const float* __restrict__ W_out, _Float16* __restrict__ Wt_out,
               float* __restrict__ ge_accum) {
    int bid = blockIdx.x;
    int tid = threadIdx.x;
    if (bid < 5000) {
        int i = (bid * 256 + tid) * 4;           // 5,120,000 elems exactly
        float s = dis[i >> 7];                   // row = i / 128
        float4 v = *(const float4*)&x[i];
        xs[i + 0] = (_Float16)(s * v.x);
        xs[i + 1] = (_Float16)(s * v.y);
        xs[i + 2] = (_Float16)(s * v.z);
        xs[i + 3] = (_Float16)(s * v.w);
    } else if (bid < 5128) {                     // W_in [128][256] -> Wt [256][128]
        int idx = (bid - 5000) * 256 + tid;      // < 32768
        int n = idx >> 7, k = idx & 127;
        Wt_in[idx] = (_Float16)W_in[(size_t)k * Hh + n];
    } else if (bid < 5384) {                     // W_mid [256][256] -> Wt [256][256]
        int idx = (bid - 5128) * 256 + tid;      // < 65536
        int n = idx >> 8, k = idx & 255;
        Wt_mid[idx] = (_Float16)W_mid[(size_t)k * Hh + n];
    } else if (bid < 5512) {                     // W_out [256][128] -> Wt [128][256]
        int idx = (bid - 5384) * 256 + tid;      // < 32768
        int n = idx >> 8, k = idx & 255;
        Wt_out[idx] = (_Float16)W_out[(size_t)k * OUTF + n];
    } else {                                     // ge_accum zero (8192)
        int idx = (bid - 5512) * 256 + tid;
        ge_accum[idx] = 0.0f;
    }
}

// ---------------- fp16 MFMA GEMM ----------------
// BR=false: C16 = fp16(dis[row] * (A @ Wt^T))           (pre-scale for next gather)
// BR=true:  C16 = fp16(relu((A @ Wt^T) + bias[col]))     (layer-1: input already propagated;
//            NO dis factor here — dis for the next propagate is applied by GEMM2's epilogue)
template <bool BR>
__global__ __launch_bounds__(256)
void k_gemm_mfma(const _Float16* __restrict__ A, const _Float16* __restrict__ Wt,
                 const float* __restrict__ dis, const float* __restrict__ bias,
                 _Float16* __restrict__ C16, int M, int N, int K) {
    __shared__ _Float16 Alds[128 * 40];
    __shared__ _Float16 Blds[128 * 40];
    const int tid = threadIdx.x;
    const int lane = tid & 63;
    const int waveId = tid >> 6;
    const int waveRow = waveId >> 1;
    const int waveCol = waveId & 1;
    const int quad = lane >> 4;
    const int m16 = lane & 15;
    const int rowBase = blockIdx.x * 128;
    const int colBase = blockIdx.y * 128;

    const int sRow  = tid >> 1;
    const int sKoff = (tid & 1) * 16;

    int gr = rowBase + sRow; if (gr >= M) gr = M - 1;
    const int gn = colBase + sRow;

    f32x4 acc[4][4];
#pragma unroll
    for (int i = 0; i < 4; ++i)
#pragma unroll
        for (int j = 0; j < 4; ++j)
            acc[i][j] = (f32x4){0.0f, 0.0f, 0.0f, 0.0f};

    for (int k0 = 0; k0 < K; k0 += 32) {
        const uint4* ap = (const uint4*)(A  + (size_t)gr * K + k0 + sKoff);
        const uint4* bp = (const uint4*)(Wt + (size_t)gn * K + k0 + sKoff);
        uint4 a0 = ap[0], a1 = ap[1];
        uint4 b0 = bp[0], b1 = bp[1];
        __syncthreads();
        *(uint4*)&Alds[sRow * 40 + sKoff]     = a0;
        *(uint4*)&Alds[sRow * 40 + sKoff + 8] = a1;
        *(uint4*)&Blds[sRow * 40 + sKoff]     = b0;
        *(uint4*)&Blds[sRow * 40 + sKoff + 8] = b1;
        __syncthreads();

        half8 a_frag[4], b_frag[4];
#pragma unroll
        for (int rt = 0; rt < 4; ++rt)
            a_frag[rt] = *(const half8*)&Alds[(waveRow * 64 + rt * 16 + m16) * 40 + quad * 8];
#pragma unroll
        for (int ct = 0; ct < 4; ++ct)
            b_frag[ct] = *(const half8*)&Blds[(waveCol * 64 + ct * 16 + m16) * 40 + quad * 8];
#pragma unroll
        for (int rt = 0; rt < 4; ++rt)
#pragma unroll
            for (int ct = 0; ct < 4; ++ct)
                acc[rt][ct] = __builtin_amdgcn_mfma_f32_16x16x32_f16(
                    a_frag[rt], b_frag[ct], acc[rt][ct], 0, 0, 0);
    }

#pragma unroll
    for (int rt = 0; rt < 4; ++rt) {
        const int rb = rowBase + waveRow * 64 + rt * 16 + quad * 4;
#pragma unroll
        for (int r = 0; r < 4; ++r) {
            const int row = rb + r;
            if (row < M) {
                const float s = dis[row];
#pragma unroll
                for (int ct = 0; ct < 4; ++ct) {
                    const int col = colBase + waveCol * 64 + ct * 16 + m16;
                    float v = acc[rt][ct][r];
                    if constexpr (BR) {
                        v = fmaxf(v + bias[col], 0.0f);      // activations, no dis
                    } else {
                        v = s * v;                            // pre-scaled h' for gather
                    }
                    C16[(size_t)row * N + col] = (_Float16)v;
                }
            }
        }
    }
}

// ---------------- CSR gather on fp16 pre-scaled rows (plain loads — nt regressed R10) ----------------
// HASBIAS: out[n] = dis[n]*(sum h'[src] + h'[n]) + bias (+ReLU)
// !HASBIAS: out[n] = fp16(dis[n]*(sum + self))   (layer-1 input-side gather)
template <int HH, bool RELU, bool H16OUT, bool HASBIAS>
__global__ __launch_bounds__(256)
void k_gatherh(const int* __restrict__ offs, const unsigned short* __restrict__ srcs,
               const float* __restrict__ dis, const _Float16* __restrict__ hp,
               const float* __restrict__ bias, void* __restrict__ outv) {
    constexpr int V = HH / 64;   // 4 (H=256) or 2 (H=128)
    typedef _Float16 halfv __attribute__((ext_vector_type(V)));
    int n = blockIdx.x * 4 + (threadIdx.x >> 6);
    if (n >= Nn) return;
    int lane = threadIdx.x & 63;
    int col = lane * V;
    int b = __builtin_amdgcn_readfirstlane(offs[n]);
    int e = __builtin_amdgcn_readfirstlane(offs[n + 1]);

    float acc[V];
    {
        halfv sv = *(const halfv*)(hp + (size_t)n * HH + col);   // self row h'[n]
#pragma unroll
        for (int j = 0; j < V; ++j) acc[j] = (float)sv[j];
    }

    int i = b;
    for (; i + 4 <= e; i += 4) {
        int s0 = srcs[i], s1 = srcs[i + 1], s2 = srcs[i + 2], s3 = srcs[i + 3];
        halfv v0 = *(const halfv*)(hp + (size_t)s0 * HH + col);
        halfv v1 = *(const halfv*)(hp + (size_t)s1 * HH + col);
        halfv v2 = *(const halfv*)(hp + (size_t)s2 * HH + col);
        halfv v3 = *(const halfv*)(hp + (size_t)s3 * HH + col);
#pragma unroll
        for (int j = 0; j < V; ++j)
            acc[j] += (float)v0[j] + (float)v1[j] + (float)v2[j] + (float)v3[j];
    }
    for (; i < e; ++i) {
        int s0 = srcs[i];
        halfv v0 = *(const halfv*)(hp + (size_t)s0 * HH + col);
#pragma unroll
        for (int j = 0; j < V; ++j) acc[j] += (float)v0[j];
    }

    float dn = dis[n];
    float r[V];
#pragma unroll
    for (int j = 0; j < V; ++j) {
        r[j] = dn * acc[j];
        if (HASBIAS) r[j] += bias[col + j];
        if (RELU) r[j] = fmaxf(r[j], 0.0f);
    }
    if constexpr (H16OUT) {
        halfv hv;
#pragma unroll
        for (int j = 0; j < V; ++j) hv[j] = (_Float16)r[j];
        *(halfv*)((_Float16*)outv + (size_t)n * HH + col) = hv;
    } else {
        if constexpr (V == 4) {
            *(float4*)((float*)outv + (size_t)n * HH + col) = make_float4(r[0], r[1], r[2], r[3]);
        } else {
            *(float2*)((float*)outv + (size_t)n * HH + col) = make_float2(r[0], r[1]);
        }
    }
}

// ---------------- pool phase 1: chunked segment-aware accumulation ----------------
__global__ __launch_bounds__(256)
void k_pool_accum(const float* __restrict__ emb, const int* __restrict__ batch,
                  float* __restrict__ ge_accum) {
    int n0 = blockIdx.x * 64;
    int nend = min(n0 + 64, Nn);
    int sub = threadIdx.x >> 6;
    int col = (threadIdx.x & 63) * 2;
    float ax = 0.0f, ay = 0.0f;
    int cur_g = -1;
    for (int n = n0 + sub; n < nend; n += 4) {
        int g = batch[n];
        if (g != cur_g) {
            if (cur_g >= 0) {
                unsafeAtomicAdd(&ge_accum[cur_g * OUTF + col], ax);
                unsafeAtomicAdd(&ge_accum[cur_g * OUTF + col + 1], ay);
            }
            cur_g = g; ax = 0.0f; ay = 0.0f;
        }
        float2 v = *(const float2*)&emb[(size_t)n * OUTF + col];
        ax += v.x; ay += v.y;
    }
    if (cur_g >= 0) {
        unsafeAtomicAdd(&ge_accum[cur_g * OUTF + col], ax);
        unsafeAtomicAdd(&ge_accum[cur_g * OUTF + col + 1], ay);
    }
}

// ---------------- fused pool finalize + logits (single block) ----------------
__global__ __launch_bounds__(256)
void k_pool_fin(const float* __restrict__ ge_accum, const int* __restrict__ batch,
                const float* __restrict__ Wc, const float* __restrict__ bc,
                float* __restrict__ ge_out, float* __restrict__ lg_out) {
    __shared__ float ge_s[Gg * OUTF];
    __shared__ int seg[Gg + 1];
    int t = threadIdx.x;
    if (t <= Gg) {                       // first index with batch >= t
        int lo = 0, hi = Nn;
        while (lo < hi) { int mid = (lo + hi) >> 1; if (batch[mid] < t) lo = mid + 1; else hi = mid; }
        seg[t] = lo;
    }
    __syncthreads();
    for (int idx = t; idx < Gg * OUTF; idx += 256) {
        int g = idx >> 7;
        float cnt = (float)(seg[g + 1] - seg[g]);
        float v = ge_accum[idx] / fmaxf(cnt, 1.0f);
        ge_s[idx] = v;
        ge_out[idx] = v;
    }
    __syncthreads();
    if (t < 128) {
        int g = t >> 1, c = t & 1;
        float s = bc[c];
        for (int k = 0; k < 128; ++k) s += ge_s[g * 128 + k] * Wc[k * 2 + c];
        lg_out[t] = s;
    }
}

extern "C" void kernel_launch(void* const* d_in, const int* in_sizes, int n_in,
                              void* d_out, int out_size, void* d_ws, size_t ws_size,
                              hipStream_t stream) {
    const float* x     = (const float*)d_in[0];
    const int*   ei    = (const int*)d_in[1];
    const int*   batch = (const int*)d_in[2];
    const float* W_in  = (const float*)d_in[3];
    const float* b_in  = (const float*)d_in[4];
    const float* W_mid = (const float*)d_in[5];
    const float* b_mid = (const float*)d_in[6];
    const float* W_out = (const float*)d_in[7];
    const float* b_out = (const float*)d_in[8];
    const float* W_cls = (const float*)d_in[9];
    const float* b_cls = (const float*)d_in[10];

    const int* src = ei;
    const int* dst = ei + Ee;

    // workspace layout (4B units), total ~63.5 MB (< proven 83.7 MB envelope)
    float* ws = (float*)d_ws;
    float* dis      = ws;                          // 40000
    int*   cnt      = (int*)(ws + 40000);          // 40000
    int*   offs     = (int*)(ws + 80000);          // 40064
    int*   partial  = (int*)(ws + 120064);         // 192
    float* ge_accum = ws + 120256;                 // 8192
    unsigned short* src_sorted = (unsigned short*)(ws + 128448);   // 640000 ushort
    _Float16* xs     = (_Float16*)(ws + 448448);   // 40000*128 h (dis-scaled x)
    _Float16* g1     = (_Float16*)(ws + 3008448);  // 40000*128 h (gathered x)
    _Float16* Wt_in  = (_Float16*)(ws + 5568448);  // 256*128 h
    _Float16* Wt_mid = (_Float16*)(ws + 5584832);  // 256*256 h
    _Float16* Wt_out = (_Float16*)(ws + 5617600);  // 128*256 h
    _Float16* hA     = (_Float16*)(ws + 5633984);  // 40000*256 h
    _Float16* actA   = (_Float16*)(ws + 10753984); // 40000*256 h
    // end = 15,873,984 floats = 63.5 MB

    float* out    = (float*)d_out;
    float* ge_out = out + (size_t)Nn * OUTF;
    float* lg_out = ge_out + Gg * OUTF;

    const int nBlkE = (Ee + 255) / 256;
    const int gRows = (Nn + 127) / 128;            // 313
    const int nBlkG = (Nn + 3) / 4;                // 10000

    // ---- CSR build ----
    (void)hipMemsetAsync(cnt, 0, Nn * sizeof(int), stream);
    k_count<<<nBlkE, 256, 0, stream>>>(dst, cnt);
    k_scan1<<<NBLK_N, 256, 0, stream>>>(cnt, offs, partial, dis);
    k_scan2<<<1, 256, 0, stream>>>(partial);
    k_scan3<<<NBLK_N, 256, 0, stream>>>(offs, partial);
    k_fill<<<nBlkE, 256, 0, stream>>>(src, dst, offs, cnt, src_sorted);

    // ---- conversions (xs = fp16(dis*x)) + ge_accum zero ----
    k_cvt_all<<<5544, 256, 0, stream>>>(x, dis, xs, W_in, Wt_in, W_mid, Wt_mid, W_out, Wt_out, ge_accum);

    // ---- layer 1: gather FIRST on 128-dim x (S(xW) == (Sx)W), then GEMM w/ bias+relu epilogue ----
    k_gatherh<INF, false, true, false><<<nBlkG, 256, 0, stream>>>(offs, src_sorted, dis, xs, nullptr, g1);
    k_gemm_mfma<true><<<dim3(gRows, Hh / 128), 256, 0, stream>>>(g1, Wt_in, dis, b_in, actA, Nn, Hh, INF);

    // ---- layer 2 ----
    k_gemm_mfma<false><<<dim3(gRows, Hh / 128), 256, 0, stream>>>(actA, Wt_mid, dis, nullptr, hA, Nn, Hh, Hh);
    k_gatherh<Hh, true, true, true><<<nBlkG, 256, 0, stream>>>(offs, src_sorted, dis, hA, b_mid, actA);

    // ---- layer 3 -> node embeddings (fp32) in d_out ----
    k_gemm_mfma<false><<<dim3(gRows, OUTF / 128), 256, 0, stream>>>(actA, Wt_out, dis, nullptr, hA, Nn, OUTF, Hh);
    k_gatherh<OUTF, false, false, true><<<nBlkG, 256, 0, stream>>>(offs, src_sorted, dis, hA, b_out, out);

    // ---- pooling + classifier ----
    k_pool_accum<<<(Nn + 63) / 64, 256, 0, stream>>>(out, batch, ge_accum);
    k_pool_fin<<<1, 256, 0, stream>>>(ge_accum, batch, W_cls, b_cls, ge_out, lg_out);
}

// Round 13
// 307.371 us; speedup vs baseline: 1.3224x; 1.0774x over previous
//
#include <hip/hip_runtime.h>
#include <hip/hip_bf16.h>

// Problem constants (from reference)
#define Nn   40000
#define Ee   640000
#define Gg   64
#define INF  128
#define Hh   256
#define OUTF 128

#define NBLK_N 157   // ceil(40000/256)

typedef _Float16 half8 __attribute__((ext_vector_type(8)));
typedef float    f32x4 __attribute__((ext_vector_type(4)));

// ---------------- degree histogram + per-edge rank ----------------
__global__ __launch_bounds__(256)
void k_count(const int* __restrict__ dst, int* __restrict__ cnt,
             unsigned short* __restrict__ rank16) {
    int e = blockIdx.x * 256 + threadIdx.x;
    if (e < Ee) rank16[e] = (unsigned short)atomicAdd(&cnt[dst[e]], 1);
}

// ---------------- scan1 + dis (fused) ----------------
__global__ __launch_bounds__(256)
void k_scan1(const int* __restrict__ cnt, int* __restrict__ offs, int* __restrict__ partial,
             float* __restrict__ dis) {
    __shared__ int sm[256];
    int i = blockIdx.x * 256 + threadIdx.x;
    int v = 0;
    if (i < Nn) {
        v = cnt[i];
        dis[i] = rsqrtf((float)v + 1.0f);
    }
    sm[threadIdx.x] = v;
    __syncthreads();
#pragma unroll
    for (int d = 1; d < 256; d <<= 1) {
        int t = (threadIdx.x >= d) ? sm[threadIdx.x - d] : 0;
        __syncthreads();
        sm[threadIdx.x] += t;
        __syncthreads();
    }
    if (i < Nn) offs[i] = sm[threadIdx.x] - v;     // block-local exclusive
    if (threadIdx.x == 255) partial[blockIdx.x] = sm[255];
}

// ---------------- mega kernel: offs fixup (scan2+scan3 fused) + all conversions ----------------
// blocks [0,157): scan partial[157] in-LDS, add base to offs
// blocks [157,157+5544): xs=fp16(dis*x) | W->Wt fp16 x3 | ge_accum zero
__global__ __launch_bounds__(256)
void k_scanB(int* __restrict__ offs, const int* __restrict__ partial,
             const float* __restrict__ x, const float* __restrict__ dis,
             _Float16* __restrict__ xs,
             const float* __restrict__ W_in,  _Float16* __restrict__ Wt_in,
             const float* __restrict__ W_mid, _Float16* __restrict__ Wt_mid,
             const float* __restrict__ W_out, _Float16* __restrict__ Wt_out,
             float* __restrict__ ge_accum) {
    int bid = blockIdx.x;
    int tid = threadIdx.x;
    if (bid < NBLK_N) {
        __shared__ int sm[256];
        int v = (tid < NBLK_N) ? partial[tid] : 0;
        sm[tid] = v;
        __syncthreads();
#pragma unroll
        for (int d = 1; d < 256; d <<= 1) {
            int t = (tid >= d) ? sm[tid - d] : 0;
            __syncthreads();
            sm[tid] += t;
            __syncthreads();
        }
        int base = (bid > 0) ? sm[bid - 1] : 0;    // exclusive prefix for this block
        int i = bid * 256 + tid;
        if (i < Nn) offs[i] += base;
        if (i == 0) offs[Nn] = Ee;
        return;
    }
    int b2 = bid - NBLK_N;
    if (b2 < 5000) {
        int i = (b2 * 256 + tid) * 4;              // 5,120,000 elems exactly
        float s = dis[i >> 7];                     // row = i / 128
        float4 v = *(const float4*)&x[i];
        xs[i + 0] = (_Float16)(s * v.x);
        xs[i + 1] = (_Float16)(s * v.y);
        xs[i + 2] = (_Float16)(s * v.z);
        xs[i + 3] = (_Float16)(s * v.w);
    } else if (b2 < 5128) {                        // W_in [128][256] -> Wt [256][128]
        int idx = (b2 - 5000) * 256 + tid;
        int n = idx >> 7, k = idx & 127;
        Wt_in[idx] = (_Float16)W_in[(size_t)k * Hh + n];
    } else if (b2 < 5384) {                        // W_mid [256][256] -> Wt [256][256]
        int idx = (b2 - 5128) * 256 + tid;
        int n = idx >> 8, k = idx & 255;
        Wt_mid[idx] = (_Float16)W_mid[(size_t)k * Hh + n];
    } else if (b2 < 5512) {                        // W_out [256][128] -> Wt [128][256]
        int idx = (b2 - 5384) * 256 + tid;
        int n = idx >> 8, k = idx & 255;
        Wt_out[idx] = (_Float16)W_out[(size_t)k * OUTF + n];
    } else {                                       // ge_accum zero (8192)
        int idx = (b2 - 5512) * 256 + tid;
        ge_accum[idx] = 0.0f;
    }
}

// ---------------- CSR fill: atomic-free (rank precomputed) ----------------
__global__ __launch_bounds__(256)
void k_fill(const int* __restrict__ src, const int* __restrict__ dst,
            const int* __restrict__ offs, const unsigned short* __restrict__ rank16,
            unsigned short* __restrict__ src_sorted) {
    int e = blockIdx.x * 256 + threadIdx.x;
    if (e >= Ee) return;
    int d = dst[e];
    src_sorted[offs[d] + rank16[e]] = (unsigned short)src[e];
}

// ---------------- fp16 MFMA GEMM ----------------
// BR=false: C16 = fp16(dis[row] * (A @ Wt^T))           (pre-scale for next gather)
// BR=true:  C16 = fp16(relu((A @ Wt^T) + bias[col]))     (layer-1 fused epilogue, no dis)
template <bool BR>
__global__ __launch_bounds__(256)
void k_gemm_mfma(const _Float16* __restrict__ A, const _Float16* __restrict__ Wt,
                 const float* __restrict__ dis, const float* __restrict__ bias,
                 _Float16* __restrict__ C16, int M, int N, int K) {
    __shared__ _Float16 Alds[128 * 40];
    __shared__ _Float16 Blds[128 * 40];
    const int tid = threadIdx.x;
    const int lane = tid & 63;
    const int waveId = tid >> 6;
    const int waveRow = waveId >> 1;
    const int waveCol = waveId & 1;
    const int quad = lane >> 4;
    const int m16 = lane & 15;
    const int rowBase = blockIdx.x * 128;
    const int colBase = blockIdx.y * 128;

    const int sRow  = tid >> 1;
    const int sKoff = (tid & 1) * 16;

    int gr = rowBase + sRow; if (gr >= M) gr = M - 1;
    const int gn = colBase + sRow;

    f32x4 acc[4][4];
#pragma unroll
    for (int i = 0; i < 4; ++i)
#pragma unroll
        for (int j = 0; j < 4; ++j)
            acc[i][j] = (f32x4){0.0f, 0.0f, 0.0f, 0.0f};

    for (int k0 = 0; k0 < K; k0 += 32) {
        const uint4* ap = (const uint4*)(A  + (size_t)gr * K + k0 + sKoff);
        const uint4* bp = (const uint4*)(Wt + (size_t)gn * K + k0 + sKoff);
        uint4 a0 = ap[0], a1 = ap[1];
        uint4 b0 = bp[0], b1 = bp[1];
        __syncthreads();
        *(uint4*)&Alds[sRow * 40 + sKoff]     = a0;
        *(uint4*)&Alds[sRow * 40 + sKoff + 8] = a1;
        *(uint4*)&Blds[sRow * 40 + sKoff]     = b0;
        *(uint4*)&Blds[sRow * 40 + sKoff + 8] = b1;
        __syncthreads();

        half8 a_frag[4], b_frag[4];
#pragma unroll
        for (int rt = 0; rt < 4; ++rt)
            a_frag[rt] = *(const half8*)&Alds[(waveRow * 64 + rt * 16 + m16) * 40 + quad * 8];
#pragma unroll
        for (int ct = 0; ct < 4; ++ct)
            b_frag[ct] = *(const half8*)&Blds[(waveCol * 64 + ct * 16 + m16) * 40 + quad * 8];
#pragma unroll
        for (int rt = 0; rt < 4; ++rt)
#pragma unroll
            for (int ct = 0; ct < 4; ++ct)
                acc[rt][ct] = __builtin_amdgcn_mfma_f32_16x16x32_f16(
                    a_frag[rt], b_frag[ct], acc[rt][ct], 0, 0, 0);
    }

#pragma unroll
    for (int rt = 0; rt < 4; ++rt) {
        const int rb = rowBase + waveRow * 64 + rt * 16 + quad * 4;
#pragma unroll
        for (int r = 0; r < 4; ++r) {
            const int row = rb + r;
            if (row < M) {
                const float s = dis[row];
#pragma unroll
                for (int ct = 0; ct < 4; ++ct) {
                    const int col = colBase + waveCol * 64 + ct * 16 + m16;
                    float v = acc[rt][ct][r];
                    if constexpr (BR) {
                        v = fmaxf(v + bias[col], 0.0f);      // activations, no dis
                    } else {
                        v = s * v;                            // pre-scaled h' for gather
                    }
                    C16[(size_t)row * N + col] = (_Float16)v;
                }
            }
        }
    }
}

// ---------------- CSR gather on fp16 pre-scaled rows (plain loads) ----------------
// HASBIAS: out[n] = dis[n]*(sum h'[src] + h'[n]) + bias (+ReLU)
// !HASBIAS: out[n] = fp16(dis[n]*(sum + self))   (layer-1 input-side gather)
template <int HH, bool RELU, bool H16OUT, bool HASBIAS>
__global__ __launch_bounds__(256)
void k_gatherh(const int* __restrict__ offs, const unsigned short* __restrict__ srcs,
               const float* __restrict__ dis, const _Float16* __restrict__ hp,
               const float* __restrict__ bias, void* __restrict__ outv) {
    constexpr int V = HH / 64;   // 4 (H=256) or 2 (H=128)
    typedef _Float16 halfv __attribute__((ext_vector_type(V)));
    int n = blockIdx.x * 4 + (threadIdx.x >> 6);
    if (n >= Nn) return;
    int lane = threadIdx.x & 63;
    int col = lane * V;
    int b = __builtin_amdgcn_readfirstlane(offs[n]);
    int e = __builtin_amdgcn_readfirstlane(offs[n + 1]);

    float acc[V];
    {
        halfv sv = *(const halfv*)(hp + (size_t)n * HH + col);   // self row h'[n]
#pragma unroll
        for (int j = 0; j < V; ++j) acc[j] = (float)sv[j];
    }

    int i = b;
    for (; i + 4 <= e; i += 4) {
        int s0 = srcs[i], s1 = srcs[i + 1], s2 = srcs[i + 2], s3 = srcs[i + 3];
        halfv v0 = *(const halfv*)(hp + (size_t)s0 * HH + col);
        halfv v1 = *(const halfv*)(hp + (size_t)s1 * HH + col);
        halfv v2 = *(const halfv*)(hp + (size_t)s2 * HH + col);
        halfv v3 = *(const halfv*)(hp + (size_t)s3 * HH + col);
#pragma unroll
        for (int j = 0; j < V; ++j)
            acc[j] += (float)v0[j] + (float)v1[j] + (float)v2[j] + (float)v3[j];
    }
    for (; i < e; ++i) {
        int s0 = srcs[i];
        halfv v0 = *(const halfv*)(hp + (size_t)s0 * HH + col);
#pragma unroll
        for (int j = 0; j < V; ++j) acc[j] += (float)v0[j];
    }

    float dn = dis[n];
    float r[V];
#pragma unroll
    for (int j = 0; j < V; ++j) {
        r[j] = dn * acc[j];
        if (HASBIAS) r[j] += bias[col + j];
        if (RELU) r[j] = fmaxf(r[j], 0.0f);
    }
    if constexpr (H16OUT) {
        halfv hv;
#pragma unroll
        for (int j = 0; j < V; ++j) hv[j] = (_Float16)r[j];
        *(halfv*)((_Float16*)outv + (size_t)n * HH + col) = hv;
    } else {
        if constexpr (V == 4) {
            *(float4*)((float*)outv + (size_t)n * HH + col) = make_float4(r[0], r[1], r[2], r[3]);
        } else {
            *(float2*)((float*)outv + (size_t)n * HH + col) = make_float2(r[0], r[1]);
        }
    }
}

// ---------------- pool phase 1: chunked segment-aware accumulation ----------------
__global__ __launch_bounds__(256)
void k_pool_accum(const float* __restrict__ emb, const int* __restrict__ batch,
                  float* __restrict__ ge_accum) {
    int n0 = blockIdx.x * 64;
    int nend = min(n0 + 64, Nn);
    int sub = threadIdx.x >> 6;
    int col = (threadIdx.x & 63) * 2;
    float ax = 0.0f, ay = 0.0f;
    int cur_g = -1;
    for (int n = n0 + sub; n < nend; n += 4) {
        int g = batch[n];
        if (g != cur_g) {
            if (cur_g >= 0) {
                unsafeAtomicAdd(&ge_accum[cur_g * OUTF + col], ax);
                unsafeAtomicAdd(&ge_accum[cur_g * OUTF + col + 1], ay);
            }
            cur_g = g; ax = 0.0f; ay = 0.0f;
        }
        float2 v = *(const float2*)&emb[(size_t)n * OUTF + col];
        ax += v.x; ay += v.y;
    }
    if (cur_g >= 0) {
        unsafeAtomicAdd(&ge_accum[cur_g * OUTF + col], ax);
        unsafeAtomicAdd(&ge_accum[cur_g * OUTF + col + 1], ay);
    }
}

// ---------------- fused pool finalize + logits (single block) ----------------
__global__ __launch_bounds__(256)
void k_pool_fin(const float* __restrict__ ge_accum, const int* __restrict__ batch,
                const float* __restrict__ Wc, const float* __restrict__ bc,
                float* __restrict__ ge_out, float* __restrict__ lg_out) {
    __shared__ float ge_s[Gg * OUTF];
    __shared__ int seg[Gg + 1];
    int t = threadIdx.x;
    if (t <= Gg) {                       // first index with batch >= t
        int lo = 0, hi = Nn;
        while (lo < hi) { int mid = (lo + hi) >> 1; if (batch[mid] < t) lo = mid + 1; else hi = mid; }
        seg[t] = lo;
    }
    __syncthreads();
    for (int idx = t; idx < Gg * OUTF; idx += 256) {
        int g = idx >> 7;
        float cnt = (float)(seg[g + 1] - seg[g]);
        float v = ge_accum[idx] / fmaxf(cnt, 1.0f);
        ge_s[idx] = v;
        ge_out[idx] = v;
    }
    __syncthreads();
    if (t < 128) {
        int g = t >> 1, c = t & 1;
        float s = bc[c];
        for (int k = 0; k < 128; ++k) s += ge_s[g * 128 + k] * Wc[k * 2 + c];
        lg_out[t] = s;
    }
}

extern "C" void kernel_launch(void* const* d_in, const int* in_sizes, int n_in,
                              void* d_out, int out_size, void* d_ws, size_t ws_size,
                              hipStream_t stream) {
    const float* x     = (const float*)d_in[0];
    const int*   ei    = (const int*)d_in[1];
    const int*   batch = (const int*)d_in[2];
    const float* W_in  = (const float*)d_in[3];
    const float* b_in  = (const float*)d_in[4];
    const float* W_mid = (const float*)d_in[5];
    const float* b_mid = (const float*)d_in[6];
    const float* W_out = (const float*)d_in[7];
    const float* b_out = (const float*)d_in[8];
    const float* W_cls = (const float*)d_in[9];
    const float* b_cls = (const float*)d_in[10];

    const int* src = ei;
    const int* dst = ei + Ee;

    // workspace layout (4B units), total ~64.8 MB (< proven 83.7 MB envelope)
    float* ws = (float*)d_ws;
    float* dis      = ws;                          // 40000
    int*   cnt      = (int*)(ws + 40000);          // 40000
    int*   offs     = (int*)(ws + 80000);          // 40064
    int*   partial  = (int*)(ws + 120064);         // 192
    float* ge_accum = ws + 120256;                 // 8192
    unsigned short* src_sorted = (unsigned short*)(ws + 128448);   // 640000 ushort
    unsigned short* rank16     = (unsigned short*)(ws + 448448);   // 640000 ushort
    _Float16* xs     = (_Float16*)(ws + 768448);   // 40000*128 h (dis-scaled x)
    _Float16* g1     = (_Float16*)(ws + 3328448);  // 40000*128 h (gathered x)
    _Float16* Wt_in  = (_Float16*)(ws + 5888448);  // 256*128 h
    _Float16* Wt_mid = (_Float16*)(ws + 5904832);  // 256*256 h
    _Float16* Wt_out = (_Float16*)(ws + 5937600);  // 128*256 h
    _Float16* hA     = (_Float16*)(ws + 5953984);  // 40000*256 h
    _Float16* actA   = (_Float16*)(ws + 11073984); // 40000*256 h
    // end = 16,193,984 floats = 64.8 MB

    float* out    = (float*)d_out;
    float* ge_out = out + (size_t)Nn * OUTF;
    float* lg_out = ge_out + Gg * OUTF;

    const int nBlkE = (Ee + 255) / 256;
    const int gRows = (Nn + 127) / 128;            // 313
    const int nBlkG = (Nn + 3) / 4;                // 10000

    // ---- CSR build + conversions (5 dispatches incl. memset) ----
    (void)hipMemsetAsync(cnt, 0, Nn * sizeof(int), stream);
    k_count<<<nBlkE, 256, 0, stream>>>(dst, cnt, rank16);
    k_scan1<<<NBLK_N, 256, 0, stream>>>(cnt, offs, partial, dis);
    k_scanB<<<NBLK_N + 5544, 256, 0, stream>>>(offs, partial, x, dis, xs,
                                               W_in, Wt_in, W_mid, Wt_mid, W_out, Wt_out, ge_accum);
    k_fill<<<nBlkE, 256, 0, stream>>>(src, dst, offs, rank16, src_sorted);

    // ---- layer 1: gather FIRST on 128-dim x (S(xW) == (Sx)W), then GEMM w/ bias+relu epilogue ----
    k_gatherh<INF, false, true, false><<<nBlkG, 256, 0, stream>>>(offs, src_sorted, dis, xs, nullptr, g1);
    k_gemm_mfma<true><<<dim3(gRows, Hh / 128), 256, 0, stream>>>(g1, Wt_in, dis, b_in, actA, Nn, Hh, INF);

    // ---- layer 2 ----
    k_gemm_mfma<false><<<dim3(gRows, Hh / 128), 256, 0, stream>>>(actA, Wt_mid, dis, nullptr, hA, Nn, Hh, Hh);
    k_gatherh<Hh, true, true, true><<<nBlkG, 256, 0, stream>>>(offs, src_sorted, dis, hA, b_mid, actA);

    // ---- layer 3 -> node embeddings (fp32) in d_out ----
    k_gemm_mfma<false><<<dim3(gRows, OUTF / 128), 256, 0, stream>>>(actA, Wt_out, dis, nullptr, hA, Nn, OUTF, Hh);
    k_gatherh<OUTF, false, false, true><<<nBlkG, 256, 0, stream>>>(offs, src_sorted, dis, hA, b_out, out);

    // ---- pooling + classifier ----
    k_pool_accum<<<(Nn + 63) / 64, 256, 0, stream>>>(out, batch, ge_accum);
    k_pool_fin<<<1, 256, 0, stream>>>(ge_accum, batch, W_cls, b_cls, ge_out, lg_out);
}